// Round 5
// baseline (87.444 us; speedup 1.0000x reference)
//
#include <hip/hip_runtime.h>
#include <hip/hip_bf16.h>
#include <math.h>

#define B_  4096
#define F_  256
#define T_  128
#define D_  6
#define U_  16
#define NB_ 64
#define N_  (T_ * D_)   // 768

typedef __attribute__((ext_vector_type(8))) short bf16x8;
typedef __attribute__((ext_vector_type(4))) float f32x4;

// fp32 -> bf16 RNE, scalar (prep only)
__device__ __forceinline__ short f2b(float f) {
    union { float f; unsigned u; } v; v.f = f;
    unsigned r = (v.u + 0x7FFFu + ((v.u >> 16) & 1u)) >> 16;
    return (short)r;
}
// packed pair fp32 -> bf16x2 (v_cvt_pk_bf16_f32 on gfx950); lo -> bits[15:0]
__device__ __forceinline__ unsigned pk2(float lo, float hi) {
    union { __hip_bfloat162 h; unsigned u; } c;
    c.h = __float22bfloat162_rn(make_float2(lo, hi));
    return c.u;
}
__device__ __forceinline__ float clamp01(float x) {
    return fminf(fmaxf(x, 0.f), 1.f);   // v_med3_f32
}

// ---------------------------------------------------------------------------
// K1 (prep):
//  blocks [0,128):  sparsemax over D=6 rows of (F*T,6); sel_t bf16 transposed
//                   to (768,256) = MFMA B-operand layout (n-major, k contig)
//  blocks [128,256): resp fp32 -> bf16
//  block 256:       tsc[n] = (exp(-lt), -th*exp(-lt))
// ---------------------------------------------------------------------------
__global__ __launch_bounds__(256) void prep(const float* __restrict__ fsl,
                                            const float* __restrict__ th,
                                            const float* __restrict__ lt,
                                            const float* __restrict__ resp,
                                            unsigned short* __restrict__ sel_t,
                                            unsigned short* __restrict__ resp_b,
                                            float2* __restrict__ tsc) {
    int bid = blockIdx.x, tid = threadIdx.x;
    if (bid < 128) {
        int r = bid * 256 + tid;              // (f,t): f = r>>7, t = r&127
        const float* zp = fsl + (size_t)r * 6;
        float v0 = zp[0], v1 = zp[1], v2 = zp[2], v3 = zp[3], v4 = zp[4], v5 = zp[5];
        float s0 = v0, s1 = v1, s2 = v2, s3 = v3, s4 = v4, s5 = v5;
#define CE(a, b) { float hi_ = fmaxf(a, b), lo_ = fminf(a, b); a = hi_; b = lo_; }
        CE(s0, s1) CE(s2, s3) CE(s4, s5)
        CE(s1, s2) CE(s3, s4)
        CE(s0, s1) CE(s2, s3) CE(s4, s5)
        CE(s1, s2) CE(s3, s4)
        CE(s0, s1) CE(s2, s3) CE(s4, s5)
        CE(s1, s2) CE(s3, s4)
#undef CE
        float cum = 0.f, num = 0.f, kz = 1.f;
        cum += s0; num = cum; kz = 1.f;
        cum += s1; if (1.f + 2.f * s1 > cum) { num = cum; kz = 2.f; }
        cum += s2; if (1.f + 3.f * s2 > cum) { num = cum; kz = 3.f; }
        cum += s3; if (1.f + 4.f * s3 > cum) { num = cum; kz = 4.f; }
        cum += s4; if (1.f + 5.f * s4 > cum) { num = cum; kz = 5.f; }
        cum += s5; if (1.f + 6.f * s5 > cum) { num = cum; kz = 6.f; }
        float tau = (num - 1.f) / kz;
        int f = r >> 7, t = r & 127;
        unsigned short* o = sel_t + f;        // column f, rows (t*6+d), stride 256
        o[(t * 6 + 0) * 256] = (unsigned short)f2b(fmaxf(v0 - tau, 0.f));
        o[(t * 6 + 1) * 256] = (unsigned short)f2b(fmaxf(v1 - tau, 0.f));
        o[(t * 6 + 2) * 256] = (unsigned short)f2b(fmaxf(v2 - tau, 0.f));
        o[(t * 6 + 3) * 256] = (unsigned short)f2b(fmaxf(v3 - tau, 0.f));
        o[(t * 6 + 4) * 256] = (unsigned short)f2b(fmaxf(v4 - tau, 0.f));
        o[(t * 6 + 5) * 256] = (unsigned short)f2b(fmaxf(v5 - tau, 0.f));
    } else if (bid < 256) {
        int i = (bid - 128) * 256 + tid;      // 32768 threads * 4 = 131072 elems
        float4 v = *(const float4*)(resp + (size_t)4 * i);
        uint2 o;
        o.x = pk2(v.x, v.y);
        o.y = pk2(v.z, v.w);
        *(uint2*)(resp_b + (size_t)4 * i) = o;
    } else {
        for (int i = tid; i < N_; i += 256) {
            float s = expf(-lt[i]);
            tsc[i] = make_float2(s, -th[i] * s);
        }
    }
}

// ---------------------------------------------------------------------------
// K2 (fused), per block of 16 batch rows (grid 256, 512 thr = 8 waves):
//  Phase 1: fv_tile(16x768) = x(16x256) @ sel(256x768) via MFMA into LDS,
//           laid out as fvs[b][t*8+d] (stride-8 per tree, row stride 1028).
//  Phase 1.5: in-place affine: fvs <- fvs*exp(-lt) - th*exp(-lt)  (tl values)
//  Phase 2: per tree: ds_read_b128 + ds_read_b64 gives the 6 tl values;
//           leaf weights built directly in MFMA A-frag layout (c bits 0-2 = j,
//           3-4 = lane>>4, 5 = frag half); two 16x16x32 bf16 MFMAs vs resp.
//           4 independent accumulator chains (2-way t-unroll x br0/br1 split).
//  fv never touches global memory.
// ---------------------------------------------------------------------------
#define FVP 1028   // row stride (1024+4): ≡4 mod 32 -> 2-way max aliasing

__global__ __launch_bounds__(512) void fused_gemm_leafsum(
        const float* __restrict__ x,                // (4096,256)
        const unsigned short* __restrict__ sel_t,   // (768,256) bf16
        const unsigned short* __restrict__ resp_b,  // (128,16,64) bf16
        const float2* __restrict__ tsc,             // (768)
        float* __restrict__ out) {                  // (4096,16)
    __shared__ float fvs[16][FVP];                  // 65.8 KB
    __shared__ float red[8][16][17];                //  8.7 KB
    int tid = threadIdx.x;
    int lane = tid & 63;
    int wave = tid >> 6;                   // 0..7
    int b0 = blockIdx.x * 16;
    int lm = lane & 15;
    int kq = lane >> 4;                    // 0..3

    // ---- Phase 1: GEMM into LDS ----
    {
        f32x4 acc[6] = {};
#pragma unroll
        for (int ks = 0; ks < 8; ks++) {
            int k0 = ks * 32 + kq * 8;
            // A-frag: rows b0+lm (all waves identical -> L1 broadcast)
            const float* ap = x + (size_t)(b0 + lm) * F_ + k0;
            float4 f0 = *(const float4*)ap;
            float4 f1 = *(const float4*)(ap + 4);
            union { bf16x8 v; unsigned u[4]; } a;
            a.u[0] = pk2(f0.x, f0.y); a.u[1] = pk2(f0.z, f0.w);
            a.u[2] = pk2(f1.x, f1.y); a.u[3] = pk2(f1.z, f1.w);
#pragma unroll
            for (int i = 0; i < 6; i++) {
                int n = (wave * 6 + i) * 16 + lm;
                bf16x8 b = *(const bf16x8*)(sel_t + (size_t)n * F_ + k0);
                acc[i] = __builtin_amdgcn_mfma_f32_16x16x32_bf16(a.v, b, acc[i], 0, 0, 0);
            }
        }
#pragma unroll
        for (int i = 0; i < 6; i++) {
            int n = (wave * 6 + i) * 16 + lm;   // output col (t,d) = (n/6, n%6)
            int t = n / 6, d = n - t * 6;
            int col = t * 8 + d;
#pragma unroll
            for (int r = 0; r < 4; r++)
                fvs[kq * 4 + r][col] = acc[i][r];   // D: row(b)=kq*4+r, col(n)
        }
    }
    __syncthreads();

    // ---- Phase 1.5: fold thresholds/temperatures in-place ----
    {
        int b = tid & 15;
        int chunk = tid >> 4;              // 0..31, covers n = chunk*24 .. +23
#pragma unroll
        for (int j = 0; j < 24; j++) {
            int n = chunk * 24 + j;
            float2 so = tsc[n];
            int col = (chunk * 4 + j / 6) * 8 + (j % 6);   // t = n/6 compile-time
            fvs[b][col] = fmaf(fvs[b][col], so.x, so.y);
        }
    }
    __syncthreads();

    // ---- Phase 2: leaf weights + response contraction ----
    f32x4 accA0 = {}, accB0 = {}, accA1 = {}, accB1 = {};
    int q0 = kq & 1, q1 = kq >> 1;         // c bits 3,4
#pragma unroll
    for (int j = 0; j < 16; j += 2) {
#pragma unroll
        for (int jj = 0; jj < 2; jj++) {
            int t = wave + (j + jj) * 8;
            float4 tl03 = *(const float4*)&fvs[lm][t * 8];       // 16B aligned
            float2 tl45 = *(const float2*)&fvs[lm][t * 8 + 4];
            float tl[6] = { tl03.x, tl03.y, tl03.z, tl03.w, tl45.x, tl45.y };
            float bp[6], bn[6];
#pragma unroll
            for (int d = 0; d < 6; d++) {
                bp[d] = clamp01(fmaf(tl[d], 0.5f, 0.5f));   // bit=0 factor
                bn[d] = 1.0f - bp[d];                        // bit=1 (Sterbenz-exact)
            }
            float p01[4] = { bp[0] * bp[1], bn[0] * bp[1], bp[0] * bn[1], bn[0] * bn[1] };
            float p3[8];
#pragma unroll
            for (int jx = 0; jx < 8; jx++) p3[jx] = p01[jx & 3] * ((jx & 4) ? bn[2] : bp[2]);
            float t34 = (q0 ? bn[3] : bp[3]) * (q1 ? bn[4] : bp[4]);
            float w0 = t34 * bp[5], w1 = t34 * bn[5];
            union { bf16x8 v; unsigned u[4]; } a0, a1;
#pragma unroll
            for (int jx = 0; jx < 4; jx++) {
                a0.u[jx] = pk2(p3[2 * jx] * w0, p3[2 * jx + 1] * w0);
                a1.u[jx] = pk2(p3[2 * jx] * w1, p3[2 * jx + 1] * w1);
            }
            const unsigned short* rbp = resp_b + (size_t)t * (U_ * NB_) + lm * NB_ + kq * 8;
            bf16x8 br0 = *(const bf16x8*)rbp;          // c = kq*8+j
            bf16x8 br1 = *(const bf16x8*)(rbp + 32);   // c += 32
            if (jj == 0) {
                accA0 = __builtin_amdgcn_mfma_f32_16x16x32_bf16(a0.v, br0, accA0, 0, 0, 0);
                accB0 = __builtin_amdgcn_mfma_f32_16x16x32_bf16(a1.v, br1, accB0, 0, 0, 0);
            } else {
                accA1 = __builtin_amdgcn_mfma_f32_16x16x32_bf16(a0.v, br0, accA1, 0, 0, 0);
                accB1 = __builtin_amdgcn_mfma_f32_16x16x32_bf16(a1.v, br1, accB1, 0, 0, 0);
            }
        }
    }
#pragma unroll
    for (int r = 0; r < 4; r++)
        red[wave][kq * 4 + r][lm] = (accA0[r] + accB0[r]) + (accA1[r] + accB1[r]);
    __syncthreads();
    if (tid < 256) {
        int row = tid >> 4, col = tid & 15;
        float s = 0.f;
#pragma unroll
        for (int w = 0; w < 8; w++) s += red[w][row][col];
        out[(size_t)(b0 + row) * U_ + col] = s;
    }
}

// ---------------------------------------------------------------------------
extern "C" void kernel_launch(void* const* d_in, const int* in_sizes, int n_in,
                              void* d_out, int out_size, void* d_ws, size_t ws_size,
                              hipStream_t stream) {
    const float* x    = (const float*)d_in[0];  // (B,F)
    const float* fsl  = (const float*)d_in[1];  // (F,T,D)
    const float* th   = (const float*)d_in[2];  // (T,D)
    const float* lt   = (const float*)d_in[3];  // (T,D)
    const float* resp = (const float*)d_in[4];  // (T,U,NB)
    float* out = (float*)d_out;                 // (B,U)

    // ws layout (662 KB)
    char* w = (char*)d_ws;
    unsigned short* sel_t  = (unsigned short*)w;              // 393,216 B (768x256)
    unsigned short* resp_b = (unsigned short*)(w + 393216);   // 262,144 B
    float2*         tsc    = (float2*)(w + 655360);           //   6,144 B

    prep<<<dim3(257), dim3(256), 0, stream>>>(fsl, th, lt, resp, sel_t, resp_b, tsc);
    fused_gemm_leafsum<<<dim3(B_ / 16), dim3(512), 0, stream>>>(x, sel_t, resp_b, tsc, out);
}